// Round 1
// baseline (443.845 us; speedup 1.0000x reference)
//
#include <hip/hip_runtime.h>

typedef float f4 __attribute__((ext_vector_type(4)));

#define CC 64
#define HH 512
#define WW 512
#define TW 16     // tile width (pixels)
#define TPX 128   // 8 rows * 16 cols
#define YP 132    // padded pitch (floats): 16B-aligned rows, 4-word bank rotation

__global__ __launch_bounds__(256, 1)
void avif_fused(const float* __restrict__ x, const float* __restrict__ twm,
                const float* __restrict__ w1, const float* __restrict__ b1,
                const float* __restrict__ w2, const float* __restrict__ b2,
                float* __restrict__ out)
{
    __shared__ float ys[CC][YP];   // x tile -> transformed Y tile, [channel][px]
    __shared__ float hs[CC][YP];   // hidden relu(W1 Y + b1)
    __shared__ float ws1[CC][CC];  // w1 row-major [o][k]
    __shared__ float ws2[CC][CC];  // w2 row-major [o][k]

    const int t = threadIdx.x;
    // decode blockIdx so that horizontally-adjacent tiles (wt, wt^1) are 8 apart
    // in bid -> same XCD (mod-8 round robin) -> shared 128B line hits L2.
    const int bid = blockIdx.x;
    const int b3 = (bid >> 3) & 1;
    const int u  = ((bid >> 4) << 3) | (bid & 7);   // 0..4095, bijective with (bid>>4, bid&7)
    const int wt = ((u & 15) << 1) | b3;            // 0..31
    const int hb = (u >> 4) & 63;                   // 0..63
    const int b  = u >> 10;                         // 0..3

    const float* xB = x + (((size_t)b * CC) * HH + (size_t)hb * 8) * WW + wt * TW;

    // ---- stage W1/W2 (linear copy: coalesced global, conflict-free LDS) ----
    {
        const f4* g1 = (const f4*)w1;
        const f4* g2 = (const f4*)w2;
        f4* s1 = (f4*)&ws1[0][0];
        f4* s2 = (f4*)&ws2[0][0];
#pragma unroll
        for (int j = 0; j < 4; ++j) {
            s1[t + j * 256] = g1[t + j * 256];
            s2[t + j * 256] = g2[t + j * 256];
        }
    }
    // ---- stage x tile -> ys[c][px], px = i*16 + w ----
#pragma unroll
    for (int j = 0; j < 8; ++j) {
        int vid = t + j * 256;            // 2048 float4 slots
        int q = vid & 3;                  // 16B quarter within 64B row
        int i = (vid >> 2) & 7;           // row in tile
        int c = vid >> 5;                 // channel
        f4 v = *(const f4*)(xB + ((size_t)c * HH + i) * WW + q * 4);
        *(f4*)&ys[c][i * TW + q * 4] = v;
    }
    __syncthreads();

    // ---- per-(c,blk) 8x8 transform Y = T P T^T, in place in ys ----
    if (t < 128) {
        const int c = t & 63, blk = t >> 6;
        float T[8][8];
        const f4* tv = (const f4*)(twm + c * 64);
#pragma unroll
        for (int r = 0; r < 8; ++r) {
            f4 a = tv[2 * r], d = tv[2 * r + 1];
#pragma unroll
            for (int j = 0; j < 4; ++j) { T[r][j] = a[j]; T[r][4 + j] = d[j]; }
        }
        float M[8][8];  // M = P * T^T
#pragma unroll
        for (int i = 0; i < 8; ++i) {
            f4 a = *(const f4*)&ys[c][i * TW + blk * 8];
            f4 d = *(const f4*)&ys[c][i * TW + blk * 8 + 4];
            float P[8];
#pragma unroll
            for (int j = 0; j < 4; ++j) { P[j] = a[j]; P[4 + j] = d[j]; }
#pragma unroll
            for (int q = 0; q < 8; ++q) {
                float s = 0.f;
#pragma unroll
                for (int j = 0; j < 8; ++j) s = fmaf(P[j], T[q][j], s);
                M[i][q] = s;
            }
        }
#pragma unroll
        for (int p = 0; p < 8; ++p) {    // Y row p = sum_i T[p][i] * M[i][:]
            f4 r0, r1;
#pragma unroll
            for (int q = 0; q < 8; ++q) {
                float s = 0.f;
#pragma unroll
                for (int i = 0; i < 8; ++i) s = fmaf(T[p][i], M[i][q], s);
                if (q < 4) r0[q] = s; else r1[q - 4] = s;
            }
            *(f4*)&ys[c][p * TW + blk * 8]     = r0;
            *(f4*)&ys[c][p * TW + blk * 8 + 4] = r1;
        }
    }
    __syncthreads();

    // ---- GEMM1: hs = relu(W1 * ys + b1), 64o x 128px, k=64 ----
    const int ot = t >> 5, pt = t & 31;
    const int o0 = ot * 8, px0 = pt * 4;

    float acc[8][4];
#pragma unroll
    for (int a = 0; a < 8; ++a)
#pragma unroll
        for (int p = 0; p < 4; ++p) acc[a][p] = 0.f;

    for (int k = 0; k < 64; k += 4) {
        f4 yv[4], wv[8];
#pragma unroll
        for (int kk = 0; kk < 4; ++kk) yv[kk] = *(const f4*)&ys[k + kk][px0];
#pragma unroll
        for (int oo = 0; oo < 8; ++oo) wv[oo] = *(const f4*)&ws1[o0 + oo][k];
#pragma unroll
        for (int oo = 0; oo < 8; ++oo)
#pragma unroll
            for (int kk = 0; kk < 4; ++kk)
#pragma unroll
                for (int p = 0; p < 4; ++p)
                    acc[oo][p] = fmaf(wv[oo][kk], yv[kk][p], acc[oo][p]);
    }
    {
        f4 bb0 = *(const f4*)(b1 + o0);
        f4 bb1 = *(const f4*)(b1 + o0 + 4);
#pragma unroll
        for (int oo = 0; oo < 8; ++oo) {
            float bo = (oo < 4) ? bb0[oo] : bb1[oo - 4];
            f4 h;
#pragma unroll
            for (int p = 0; p < 4; ++p) h[p] = fmaxf(acc[oo][p] + bo, 0.f);
            *(f4*)&hs[o0 + oo][px0] = h;
        }
    }
    __syncthreads();

    // ---- GEMM2: z = W2 * hs + b2 ; out = ys * sigmoid(z) ----
#pragma unroll
    for (int a = 0; a < 8; ++a)
#pragma unroll
        for (int p = 0; p < 4; ++p) acc[a][p] = 0.f;

    for (int k = 0; k < 64; k += 4) {
        f4 yv[4], wv[8];
#pragma unroll
        for (int kk = 0; kk < 4; ++kk) yv[kk] = *(const f4*)&hs[k + kk][px0];
#pragma unroll
        for (int oo = 0; oo < 8; ++oo) wv[oo] = *(const f4*)&ws2[o0 + oo][k];
#pragma unroll
        for (int oo = 0; oo < 8; ++oo)
#pragma unroll
            for (int kk = 0; kk < 4; ++kk)
#pragma unroll
                for (int p = 0; p < 4; ++p)
                    acc[oo][p] = fmaf(wv[oo][kk], yv[kk][p], acc[oo][p]);
    }
    {
        f4 bb0 = *(const f4*)(b2 + o0);
        f4 bb1 = *(const f4*)(b2 + o0 + 4);
        const int hrow = px0 >> 4;        // 0..7
        const int wcol = px0 & 15;        // 0,4,8,12
        float* oB = out + (((size_t)b * CC) * HH + (size_t)(hb * 8 + hrow)) * WW
                    + wt * TW + wcol;
#pragma unroll
        for (int oo = 0; oo < 8; ++oo) {
            float bo = (oo < 4) ? bb0[oo] : bb1[oo - 4];
            f4 yv = *(const f4*)&ys[o0 + oo][px0];
            f4 r;
#pragma unroll
            for (int p = 0; p < 4; ++p) {
                float z = acc[oo][p] + bo;
                float g = 1.0f / (1.0f + __expf(-z));
                r[p] = yv[p] * g;
            }
            *(f4*)(oB + (size_t)(o0 + oo) * HH * WW) = r;
        }
    }
}

extern "C" void kernel_launch(void* const* d_in, const int* in_sizes, int n_in,
                              void* d_out, int out_size, void* d_ws, size_t ws_size,
                              hipStream_t stream) {
    (void)in_sizes; (void)n_in; (void)out_size; (void)d_ws; (void)ws_size;
    const float* x   = (const float*)d_in[0];
    const float* twm = (const float*)d_in[1];
    const float* w1  = (const float*)d_in[2];
    const float* b1  = (const float*)d_in[3];
    const float* w2  = (const float*)d_in[4];
    const float* b2  = (const float*)d_in[5];
    float* out = (float*)d_out;

    avif_fused<<<dim3(4 * 64 * 32), dim3(256), 0, stream>>>(x, twm, w1, b1, w2, b2, out);
}

// Round 3
// 282.001 us; speedup vs baseline: 1.5739x; 1.5739x over previous
//
#include <hip/hip_runtime.h>

typedef float f4 __attribute__((ext_vector_type(4)));
typedef __attribute__((ext_vector_type(4))) float f32x4;
typedef __attribute__((ext_vector_type(8))) short bf8;

__device__ __forceinline__ ushort f2bf(float f) {
    union { float f; unsigned u; } v; v.f = f;
    return (ushort)((v.u + 0x7FFFu + ((v.u >> 16) & 1u)) >> 16);
}
__device__ __forceinline__ float bf2f(unsigned hu16) {
    union { unsigned u; float f; } v; v.u = hu16 << 16;
    return v.f;
}
__device__ __forceinline__ void split2(float v, ushort& hi, ushort& lo) {
    hi = f2bf(v);
    lo = f2bf(v - bf2f((unsigned)hi));
}

__global__ __launch_bounds__(256, 2)
void avif_mfma2(const float* __restrict__ x, const float* __restrict__ twm,
                const float* __restrict__ w1, const float* __restrict__ b1,
                const float* __restrict__ w2, const float* __restrict__ b2,
                float* __restrict__ out)
{
    // split-bf16 planes, XOR-swizzled on the 8-ushort (16B) granule:
    // element (px, c) lives at row px, ushort index ((c>>3)^(px&7))*8 + (c&7)
    __shared__ ushort ysh[128][64];   // Y hi
    __shared__ ushort ysl[128][64];   // Y lo
    __shared__ ushort hsh[128][64];   // H hi
    __shared__ ushort hsl[128][64];   // H lo

    const int t = threadIdx.x;
    const int bid = blockIdx.x;
    // XCD-friendly decode (verified in round 1)
    const int b3 = (bid >> 3) & 1;
    const int u  = ((bid >> 4) << 3) | (bid & 7);
    const int wt = ((u & 15) << 1) | b3;   // 0..31
    const int hb = (u >> 4) & 63;          // 0..63
    const int b  = u >> 10;                // 0..3

    const int wv   = t >> 6;    // wave 0..3 -> output rows 16w..16w+15
    const int lane = t & 63;
    const int li   = lane & 15; // n-col within 16x16 tile
    const int lg   = lane >> 4; // k-group / row-group
    const int l7   = li & 7;

    // ---- phase 1: per-(c,blk) 8x8 transform, global -> regs -> LDS (split bf16) ----
    if (t < 128) {
        const int c = t & 63, blk = t >> 6;
        const float* xB = x + ((size_t)(b * 64 + c) * 512 + hb * 8) * 512 + wt * 16 + blk * 8;
        float P[8][8];
#pragma unroll
        for (int i = 0; i < 8; ++i) {
            f4 a = *(const f4*)(xB + i * 512);
            f4 d = *(const f4*)(xB + i * 512 + 4);
#pragma unroll
            for (int q = 0; q < 4; ++q) { P[i][q] = a[q]; P[i][4 + q] = d[q]; }
        }
        float T[8][8];
        const f4* tv = (const f4*)(twm + c * 64);
#pragma unroll
        for (int r = 0; r < 8; ++r) {
            f4 a = tv[2 * r], d = tv[2 * r + 1];
#pragma unroll
            for (int q = 0; q < 4; ++q) { T[r][q] = a[q]; T[r][4 + q] = d[q]; }
        }
        // M = P * T^T (in place, row-local)
#pragma unroll
        for (int i = 0; i < 8; ++i) {
            float m[8];
#pragma unroll
            for (int q = 0; q < 8; ++q) {
                float s = 0.f;
#pragma unroll
                for (int j2 = 0; j2 < 8; ++j2) s = fmaf(P[i][j2], T[q][j2], s);
                m[q] = s;
            }
#pragma unroll
            for (int q = 0; q < 8; ++q) P[i][q] = m[q];
        }
        // Y = T * M -> split bf16, swizzled store ys[px][swz(c)]
        const int cg = c >> 3, c7 = c & 7;
#pragma unroll
        for (int p = 0; p < 8; ++p) {
            const int px0 = p * 16 + blk * 8;
#pragma unroll
            for (int q = 0; q < 8; ++q) {
                float s = 0.f;
#pragma unroll
                for (int i = 0; i < 8; ++i) s = fmaf(T[p][i], P[i][q], s);
                ushort hi, lo; split2(s, hi, lo);
                const int idx = ((cg ^ q) << 3) | c7;   // px&7 == q here
                ysh[px0 + q][idx] = hi;
                ysl[px0 + q][idx] = lo;
            }
        }
    }

    // ---- W fragments (hi+lo) in registers; each wave needs only its 16 rows ----
    bf8 w1h[2], w1l[2], w2h[2], w2l[2];
    {
        const float* p1 = w1 + (16 * wv + li) * 64 + lg * 8;
        const float* p2 = w2 + (16 * wv + li) * 64 + lg * 8;
#pragma unroll
        for (int kk = 0; kk < 2; ++kk) {
            f4 a = *(const f4*)(p1 + kk * 32);
            f4 d = *(const f4*)(p1 + kk * 32 + 4);
            bf8 fh, fl; ushort hi, lo;
#pragma unroll
            for (int q = 0; q < 4; ++q) {
                split2(a[q], hi, lo); fh[q] = (short)hi; fl[q] = (short)lo;
                split2(d[q], hi, lo); fh[4 + q] = (short)hi; fl[4 + q] = (short)lo;
            }
            w1h[kk] = fh; w1l[kk] = fl;
            a = *(const f4*)(p2 + kk * 32);
            d = *(const f4*)(p2 + kk * 32 + 4);
#pragma unroll
            for (int q = 0; q < 4; ++q) {
                split2(a[q], hi, lo); fh[q] = (short)hi; fl[q] = (short)lo;
                split2(d[q], hi, lo); fh[4 + q] = (short)hi; fl[4 + q] = (short)lo;
            }
            w2h[kk] = fh; w2l[kk] = fl;
        }
    }
    const int o0 = 16 * wv + 4 * lg;
    const f4 b1v = *(const f4*)(b1 + o0);
    const f4 b2v = *(const f4*)(b2 + o0);
    // swizzle constants for this lane's B-fragment / output-column accesses
    const int sg0 = ((lg)     ^ l7) << 3;   // k-half 0, group = lg
    const int sg1 = ((4 + lg) ^ l7) << 3;   // k-half 1, group = 4+lg
    const int go  = o0 >> 3, co = 4 * (lg & 1);

    __syncthreads();

    // ---- GEMM1: H = relu(W1 * Y + b1), split-bf16 (3 MFMA per K=32) ----
    f32x4 acc[8];
#pragma unroll
    for (int j = 0; j < 8; ++j) acc[j] = (f32x4){0.f, 0.f, 0.f, 0.f};
#pragma unroll
    for (int j = 0; j < 8; ++j) {
        const int row = 16 * j + li;
        bf8 bh0 = *(const bf8*)&ysh[row][sg0];
        bf8 bl0 = *(const bf8*)&ysl[row][sg0];
        bf8 bh1 = *(const bf8*)&ysh[row][sg1];
        bf8 bl1 = *(const bf8*)&ysl[row][sg1];
        acc[j] = __builtin_amdgcn_mfma_f32_16x16x32_bf16(w1h[0], bh0, acc[j], 0, 0, 0);
        acc[j] = __builtin_amdgcn_mfma_f32_16x16x32_bf16(w1h[0], bl0, acc[j], 0, 0, 0);
        acc[j] = __builtin_amdgcn_mfma_f32_16x16x32_bf16(w1l[0], bh0, acc[j], 0, 0, 0);
        acc[j] = __builtin_amdgcn_mfma_f32_16x16x32_bf16(w1h[1], bh1, acc[j], 0, 0, 0);
        acc[j] = __builtin_amdgcn_mfma_f32_16x16x32_bf16(w1h[1], bl1, acc[j], 0, 0, 0);
        acc[j] = __builtin_amdgcn_mfma_f32_16x16x32_bf16(w1l[1], bh1, acc[j], 0, 0, 0);
    }
#pragma unroll
    for (int j = 0; j < 8; ++j) {
        const int px = 16 * j + li;
        const int idx = ((go ^ l7) << 3) + co;
        ushort h0h, h0l, h1h, h1l;
        split2(fmaxf(acc[j][0] + b1v[0], 0.f), h0h, h0l);
        split2(fmaxf(acc[j][1] + b1v[1], 0.f), h1h, h1l);
        *(unsigned*)&hsh[px][idx] = (unsigned)h0h | ((unsigned)h1h << 16);
        *(unsigned*)&hsl[px][idx] = (unsigned)h0l | ((unsigned)h1l << 16);
        split2(fmaxf(acc[j][2] + b1v[2], 0.f), h0h, h0l);
        split2(fmaxf(acc[j][3] + b1v[3], 0.f), h1h, h1l);
        *(unsigned*)&hsh[px][idx + 2] = (unsigned)h0h | ((unsigned)h1h << 16);
        *(unsigned*)&hsl[px][idx + 2] = (unsigned)h0l | ((unsigned)h1l << 16);
    }
    __syncthreads();

    // ---- GEMM2: Z = W2 * H + b2 ; out = Y_fp32 * sigmoid(Z) ----
#pragma unroll
    for (int j = 0; j < 8; ++j) acc[j] = (f32x4){0.f, 0.f, 0.f, 0.f};
#pragma unroll
    for (int j = 0; j < 8; ++j) {
        const int row = 16 * j + li;
        bf8 bh0 = *(const bf8*)&hsh[row][sg0];
        bf8 bl0 = *(const bf8*)&hsl[row][sg0];
        bf8 bh1 = *(const bf8*)&hsh[row][sg1];
        bf8 bl1 = *(const bf8*)&hsl[row][sg1];
        acc[j] = __builtin_amdgcn_mfma_f32_16x16x32_bf16(w2h[0], bh0, acc[j], 0, 0, 0);
        acc[j] = __builtin_amdgcn_mfma_f32_16x16x32_bf16(w2h[0], bl0, acc[j], 0, 0, 0);
        acc[j] = __builtin_amdgcn_mfma_f32_16x16x32_bf16(w2l[0], bh0, acc[j], 0, 0, 0);
        acc[j] = __builtin_amdgcn_mfma_f32_16x16x32_bf16(w2h[1], bh1, acc[j], 0, 0, 0);
        acc[j] = __builtin_amdgcn_mfma_f32_16x16x32_bf16(w2h[1], bl1, acc[j], 0, 0, 0);
        acc[j] = __builtin_amdgcn_mfma_f32_16x16x32_bf16(w2l[1], bh1, acc[j], 0, 0, 0);
    }
    float* outB = out + (size_t)b * 64 * 262144 + (size_t)(hb * 8) * 512 + wt * 16 + li;
#pragma unroll
    for (int j = 0; j < 8; ++j) {
        const int px = 16 * j + li;
        const int idx = ((go ^ l7) << 3) + co;
        unsigned a0 = *(const unsigned*)&ysh[px][idx];
        unsigned a1 = *(const unsigned*)&ysh[px][idx + 2];
        unsigned c0 = *(const unsigned*)&ysl[px][idx];
        unsigned c1 = *(const unsigned*)&ysl[px][idx + 2];
        float yy[4];
        yy[0] = bf2f(a0 & 0xFFFFu) + bf2f(c0 & 0xFFFFu);
        yy[1] = bf2f(a0 >> 16)     + bf2f(c0 >> 16);
        yy[2] = bf2f(a1 & 0xFFFFu) + bf2f(c1 & 0xFFFFu);
        yy[3] = bf2f(a1 >> 16)     + bf2f(c1 >> 16);
#pragma unroll
        for (int r = 0; r < 4; ++r) {
            float z = acc[j][r] + b2v[r];
            float g = 1.f / (1.f + __expf(-z));
            outB[(size_t)(o0 + r) * 262144 + j * 512] = yy[r] * g;
        }
    }
}

extern "C" void kernel_launch(void* const* d_in, const int* in_sizes, int n_in,
                              void* d_out, int out_size, void* d_ws, size_t ws_size,
                              hipStream_t stream) {
    (void)in_sizes; (void)n_in; (void)out_size; (void)d_ws; (void)ws_size;
    const float* x   = (const float*)d_in[0];
    const float* twm = (const float*)d_in[1];
    const float* w1  = (const float*)d_in[2];
    const float* b1  = (const float*)d_in[3];
    const float* w2  = (const float*)d_in[4];
    const float* b2  = (const float*)d_in[5];
    float* out = (float*)d_out;

    avif_mfma2<<<dim3(4 * 64 * 32), dim3(256), 0, stream>>>(x, twm, w1, b1, w2, b2, out);
}